// Round 6
// baseline (1055.529 us; speedup 1.0000x reference)
//
#include <hip/hip_runtime.h>

typedef float v2f __attribute__((ext_vector_type(2)));
typedef float v4f __attribute__((ext_vector_type(4)));

#define HID 30
#define TSTEPS 2048
#define BATCH 512
#define L2E 1.4426950408889634f

__device__ __forceinline__ float fexp2(float x) { return __builtin_amdgcn_exp2f(x); }
__device__ __forceinline__ float frcp(float x)  { return __builtin_amdgcn_rcpf(x); }
__device__ __forceinline__ void  pinf(float& v) { asm("" : "+v"(v)); }

// broadcast lane l of v to all lanes (constant l) — VALU, result lands in SGPR
__device__ __forceinline__ float rl(float v, int l) {
    return __int_as_float(__builtin_amdgcn_readlane(__float_as_int(v), l));
}

// p from the other 32-lane half (lane ^ 32) via gfx950 VALU permlane32_swap.
// ISA: exchanges DST.row1 <-> SRC.row0. With both operands = p:
//   ret0 = {p.row0, p.row0} -> ret0[l] = p[l&31]      (what h=1 lanes need)
//   ret1 = {p.row1, p.row1} -> ret1[l] = p[32+(l&31)] (what h=0 lanes need)
// R5 BUG was the select reversed; correct is h ? ret0 : ret1.
__device__ __forceinline__ float other_half(float p, int h) {
#if __has_builtin(__builtin_amdgcn_permlane32_swap)
    auto r = __builtin_amdgcn_permlane32_swap(__float_as_uint(p), __float_as_uint(p),
                                              false, false);
    return __uint_as_float(h ? r[0] : r[1]);
#else
    return __shfl_xor(p, 32);
#endif
}

// Wave-wide sum via DPP (VALU pipe; off the recurrence path). Valid in lane 63.
__device__ __forceinline__ float dpp_reduce63(float x) {
    x += __int_as_float(__builtin_amdgcn_update_dpp(0, __float_as_int(x), 0x111, 0xf, 0xf, true));
    x += __int_as_float(__builtin_amdgcn_update_dpp(0, __float_as_int(x), 0x112, 0xf, 0xf, true));
    x += __int_as_float(__builtin_amdgcn_update_dpp(0, __float_as_int(x), 0x114, 0xf, 0xf, true));
    x += __int_as_float(__builtin_amdgcn_update_dpp(0, __float_as_int(x), 0x118, 0xf, 0xf, true));
    x += __int_as_float(__builtin_amdgcn_update_dpp(0, __float_as_int(x), 0x142, 0xf, 0xf, true));
    x += __int_as_float(__builtin_amdgcn_update_dpp(0, __float_as_int(x), 0x143, 0xf, 0xf, true));
    return x;
}

// Block-per-batch 3-wave pipelined LSTM (one barrier per step):
//   wave0: layer1 step tt        (h1 self-recurrence in registers via readlane)
//   wave1: partial W_ih2*h1+b2 for step tt-1   (h1 via LDS chunks)
//   wave2: W_hh2*h2 + gates + fc for step tt-2 (h2 self-recurrence via readlane)
// All waves share the SAME two 30-float weight arrays (different values per wave)
// so the kernel-wide live set stays ~95 VGPRs -> no spills (R4 lesson).
// lane = (k=lane&31, h=lane>>5); gates {i,g} on h=0, {f,o} on h=1 -> one cross-half
// exchange (the i*g product) per layer-step.
__global__ __launch_bounds__(192, 1)
void lstm2_kernel(const float* __restrict__ x,
                  const float* __restrict__ w_ih1, const float* __restrict__ w_hh1,
                  const float* __restrict__ b_ih1, const float* __restrict__ b_hh1,
                  const float* __restrict__ w_ih2, const float* __restrict__ w_hh2,
                  const float* __restrict__ b_ih2, const float* __restrict__ b_hh2,
                  const float* __restrict__ w_fc,  const float* __restrict__ b_fc,
                  float* __restrict__ out)
{
    const int b    = blockIdx.x;
    const int tid  = threadIdx.x;
    const int wave = tid >> 6;
    const int lane = tid & 63;
    const int k    = lane & 31;
    const int h    = lane >> 5;
    const int kk   = (k < HID) ? k : (HID - 1);  // lanes k=30,31 duplicate unit 29
    const int rowA = h * 30 + kk;                // h0: i-row, h1: f-row
    const int rowB = 60 + h * 30 + kk;           // h0: g-row, h1: o-row

    __shared__ __align__(16) float h1buf[2][32];   // h1(t) at parity t&1 (30 used)
    __shared__ __align__(16) float pbuf[2][128];   // partial pairs, parity (t)&1
    if (tid < 64) ((float*)h1buf)[tid] = 0.0f;
    for (int i = tid; i < 256; i += 192) ((float*)pbuf)[i] = 0.0f;
    __syncthreads();

    // ---- shared-name per-wave weights: union live set stays ~60 regs ----
    float wr0[30], wr1[30];   // wave0: whh1 rowA/rowB; wave1: wih2; wave2: whh2
    float bb0 = 0.0f, bb1 = 0.0f;   // wave0: b1 rows; wave1: b2 rows
    float wxa = 0.0f, wxb = 0.0f;   // wave0 only: w_ih1 rows
    float wfck = 0.0f;              // wave2 only
    if (wave == 0) {
#pragma unroll
        for (int j = 0; j < 30; ++j) {
            wr0[j] = w_hh1[rowA * HID + j];
            wr1[j] = w_hh1[rowB * HID + j];
        }
        bb0 = b_ih1[rowA] + b_hh1[rowA];
        bb1 = b_ih1[rowB] + b_hh1[rowB];
        wxa = w_ih1[rowA];
        wxb = w_ih1[rowB];
    } else if (wave == 1) {
#pragma unroll
        for (int j = 0; j < 30; ++j) {
            wr0[j] = w_ih2[rowA * HID + j];
            wr1[j] = w_ih2[rowB * HID + j];
        }
        bb0 = b_ih2[rowA] + b_hh2[rowA];
        bb1 = b_ih2[rowB] + b_hh2[rowB];
    } else {
#pragma unroll
        for (int j = 0; j < 30; ++j) {
            wr0[j] = w_hh2[rowA * HID + j];
            wr1[j] = w_hh2[rowB * HID + j];
        }
        wfck = (h && k < HID) ? w_fc[k] : 0.0f;
    }
#pragma unroll
    for (int j = 0; j < 30; ++j) { pinf(wr0[j]); pinf(wr1[j]); }
    pinf(bb0); pinf(bb1); pinf(wxa); pinf(wxb); pinf(wfck);
    const float bfc = b_fc[0];

    // gate-y activation constants: h0 -> tanh (g), h1 -> sigmoid (o)
    const float cy = h ? (-L2E) : (-2.0f * L2E);
    const float my = h ? 1.0f : 2.0f;
    const float ay = h ? 0.0f : -1.0f;

    float hh  = 0.0f;   // wave0: h1[kk] (valid in h=1 half); wave2: h2[kk]
    float cst = 0.0f;   // wave0: c1;    wave2: c2   (valid in h=1 half)
    float xv  = 0.0f;
    const float* xp   = x   + (size_t)b * TSTEPS;
    float*       outp = out + (size_t)b * TSTEPS;

    for (int tt = 0; tt <= TSTEPS + 1; ++tt) {
        __syncthreads();   // orders h1buf (w0->w1) and pbuf (w1->w2) handoffs + WAR

        if (wave == 0) {
            if (tt < TSTEPS) {
                // ---------- layer 1, step tt (register self-recurrence) ----------
                if ((tt & 63) == 0) xv = xp[tt + lane];
                const float xt = rl(xv, tt & 63);
                float a0 = fmaf(xt, wxa, bb0), a1 = 0.0f;   // rowA: i/f
                float c0 = fmaf(xt, wxb, bb1), c1a = 0.0f;  // rowB: g/o
#pragma unroll
                for (int j = 0; j < 30; j += 2) {
                    const float hj0 = rl(hh, 32 + j);       // h1(tt-1)[j]
                    const float hj1 = rl(hh, 33 + j);
                    a0  = fmaf(wr0[j],     hj0, a0);
                    c0  = fmaf(wr1[j],     hj0, c0);
                    a1  = fmaf(wr0[j + 1], hj1, a1);
                    c1a = fmaf(wr1[j + 1], hj1, c1a);
                }
                const float preA = a0 + a1, preB = c0 + c1a;
                const float gx = frcp(1.0f + fexp2(preA * (-L2E)));           // i / f
                const float gy = fmaf(frcp(1.0f + fexp2(preB * cy)), my, ay); // g / o
                const float p  = gx * gy;                    // h0: i*g
                const float px = other_half(p, h);
                cst = fmaf(gx, cst, px);                     // h1: f*c1 + i*g
                const float tc = fmaf(2.0f, frcp(1.0f + fexp2(cst * (-2.0f * L2E))), -1.0f);
                hh = gy * tc;                                // h1: h1(tt)[kk]
                if (h) h1buf[tt & 1][kk] = hh;               // publish for wave1
            }
        } else if (wave == 1) {
            if (tt >= 1 && tt <= TSTEPS) {
                // ---------- partial: W_ih2 * h1(tt-1) + b2 ----------
                const v4f* rd = (const v4f*)h1buf[(tt - 1) & 1];
                float a0 = bb0, a1 = 0.0f;     // rowA partial
                float c0 = bb1, c1a = 0.0f;    // rowB partial
#pragma unroll
                for (int c = 0; c < 7; ++c) {
                    const v4f hc = rd[c];                    // broadcast read
                    a0  = fmaf(wr0[4 * c + 0], hc.x, a0);
                    c0  = fmaf(wr1[4 * c + 0], hc.x, c0);
                    a1  = fmaf(wr0[4 * c + 1], hc.y, a1);
                    c1a = fmaf(wr1[4 * c + 1], hc.y, c1a);
                    a0  = fmaf(wr0[4 * c + 2], hc.z, a0);
                    c0  = fmaf(wr1[4 * c + 2], hc.z, c0);
                    a1  = fmaf(wr0[4 * c + 3], hc.w, a1);
                    c1a = fmaf(wr1[4 * c + 3], hc.w, c1a);
                }
                const v2f tl = ((const v2f*)h1buf[(tt - 1) & 1])[14];  // j=28,29
                a0  = fmaf(wr0[28], tl.x, a0);
                c0  = fmaf(wr1[28], tl.x, c0);
                a1  = fmaf(wr0[29], tl.y, a1);
                c1a = fmaf(wr1[29], tl.y, c1a);
                v2f pr;
                pr.x = a0 + a1;
                pr.y = c0 + c1a;
                ((v2f*)pbuf[(tt - 1) & 1])[lane] = pr;       // handoff to wave2
            }
        } else {
            if (tt >= 2) {
                // ---------- layer 2, step tt-2 (register self-recurrence) ----------
                const v2f part = ((const v2f*)pbuf[tt & 1])[lane];  // (tt-2)&1 == tt&1
                float a0 = 0.0f, a1 = 0.0f, c0 = 0.0f, c1a = 0.0f;
#pragma unroll
                for (int j = 0; j < 30; j += 2) {
                    const float hj0 = rl(hh, 32 + j);        // h2(tt-3)[j]
                    const float hj1 = rl(hh, 33 + j);
                    a0  = fmaf(wr0[j],     hj0, a0);
                    c0  = fmaf(wr1[j],     hj0, c0);
                    a1  = fmaf(wr0[j + 1], hj1, a1);
                    c1a = fmaf(wr1[j + 1], hj1, c1a);
                }
                const float preA = (a0 + a1) + part.x;
                const float preB = (c0 + c1a) + part.y;
                const float gx = frcp(1.0f + fexp2(preA * (-L2E)));
                const float gy = fmaf(frcp(1.0f + fexp2(preB * cy)), my, ay);
                const float p  = gx * gy;
                const float px = other_half(p, h);
                cst = fmaf(gx, cst, px);                     // c2
                const float tc = fmaf(2.0f, frcp(1.0f + fexp2(cst * (-2.0f * L2E))), -1.0f);
                hh = gy * tc;                                // h2(tt-2)[kk] in h=1
                const float s = dpp_reduce63(wfck * hh);     // fc head
                if (lane == 63) outp[tt - 2] = s + bfc;
            }
        }
    }
}

extern "C" void kernel_launch(void* const* d_in, const int* in_sizes, int n_in,
                              void* d_out, int out_size, void* d_ws, size_t ws_size,
                              hipStream_t stream)
{
    const float* x     = (const float*)d_in[0];
    const float* w_ih1 = (const float*)d_in[1];
    const float* w_hh1 = (const float*)d_in[2];
    const float* b_ih1 = (const float*)d_in[3];
    const float* b_hh1 = (const float*)d_in[4];
    const float* w_ih2 = (const float*)d_in[5];
    const float* w_hh2 = (const float*)d_in[6];
    const float* b_ih2 = (const float*)d_in[7];
    const float* b_hh2 = (const float*)d_in[8];
    const float* w_fc  = (const float*)d_in[9];
    const float* b_fc  = (const float*)d_in[10];
    float* out = (float*)d_out;

    lstm2_kernel<<<BATCH, 192, 0, stream>>>(x, w_ih1, w_hh1, b_ih1, b_hh1,
                                            w_ih2, w_hh2, b_ih2, b_hh2,
                                            w_fc, b_fc, out);
}

// Round 8
// 1007.724 us; speedup vs baseline: 1.0474x; 1.0474x over previous
//
#include <hip/hip_runtime.h>

typedef float v2f __attribute__((ext_vector_type(2)));
typedef float v4f __attribute__((ext_vector_type(4)));

#define HID 30
#define TSTEPS 2048
#define BATCH 512
#define L2E 1.4426950408889634f

__device__ __forceinline__ float fexp2(float x) { return __builtin_amdgcn_exp2f(x); }
__device__ __forceinline__ float frcp(float x)  { return __builtin_amdgcn_rcpf(x); }
__device__ __forceinline__ void  pinf(float& v) { asm("" : "+v"(v)); }

// broadcast lane l of v to all lanes — VALU, result lands in SGPR
__device__ __forceinline__ float rl(float v, int l) {
    return __int_as_float(__builtin_amdgcn_readlane(__float_as_int(v), l));
}

// LDS-ordering barrier WITHOUT the vmcnt(0) drain __syncthreads() implies.
// Global stores/loads stay in flight across iterations (R6 lesson: the implicit
// vmcnt(0) before s_barrier serialized every iteration on a store ack).
__device__ __forceinline__ void lds_barrier() {
    asm volatile("s_waitcnt lgkmcnt(0)\n\ts_barrier" ::: "memory");
}

// p from the other 32-lane half (lane ^ 32) via gfx950 VALU permlane32_swap.
//   ret0 = {p.row0, p.row0} -> what h=1 lanes need
//   ret1 = {p.row1, p.row1} -> what h=0 lanes need
__device__ __forceinline__ float other_half(float p, int h) {
#if __has_builtin(__builtin_amdgcn_permlane32_swap)
    auto r = __builtin_amdgcn_permlane32_swap(__float_as_uint(p), __float_as_uint(p),
                                              false, false);
    return __uint_as_float(h ? r[0] : r[1]);
#else
    return __shfl_xor(p, 32);
#endif
}

// Wave-wide sum via DPP (VALU pipe). Valid in lane 63.
__device__ __forceinline__ float dpp_reduce63(float x) {
    x += __int_as_float(__builtin_amdgcn_update_dpp(0, __float_as_int(x), 0x111, 0xf, 0xf, true));
    x += __int_as_float(__builtin_amdgcn_update_dpp(0, __float_as_int(x), 0x112, 0xf, 0xf, true));
    x += __int_as_float(__builtin_amdgcn_update_dpp(0, __float_as_int(x), 0x114, 0xf, 0xf, true));
    x += __int_as_float(__builtin_amdgcn_update_dpp(0, __float_as_int(x), 0x118, 0xf, 0xf, true));
    x += __int_as_float(__builtin_amdgcn_update_dpp(0, __float_as_int(x), 0x142, 0xf, 0xf, true));
    x += __int_as_float(__builtin_amdgcn_update_dpp(0, __float_as_int(x), 0x143, 0xf, 0xf, true));
    return x;
}

// Block-per-batch 3-wave pipelined LSTM (one LDS barrier per step):
//   wave0: layer1 step tt        (h1 self-recurrence in registers via readlane)
//   wave1: partial W_ih2*h1+b2 for step tt-1   (h1 via LDS chunks)
//   wave2: W_hh2*h2 + gates + fc for step tt-2 (h2 self-recurrence via readlane)
// Per-step scalar fc store stays IN FLIGHT (no vmcnt drain at the barrier);
// x is double-buffered 64 steps ahead -> no exposed vmem latency in steady state.
__global__ __launch_bounds__(192, 1)
void lstm2_kernel(const float* __restrict__ x,
                  const float* __restrict__ w_ih1, const float* __restrict__ w_hh1,
                  const float* __restrict__ b_ih1, const float* __restrict__ b_hh1,
                  const float* __restrict__ w_ih2, const float* __restrict__ w_hh2,
                  const float* __restrict__ b_ih2, const float* __restrict__ b_hh2,
                  const float* __restrict__ w_fc,  const float* __restrict__ b_fc,
                  float* __restrict__ out)
{
    const int b    = blockIdx.x;
    const int tid  = threadIdx.x;
    const int wave = tid >> 6;
    const int lane = tid & 63;
    const int k    = lane & 31;
    const int h    = lane >> 5;
    const int kk   = (k < HID) ? k : (HID - 1);  // lanes k=30,31 duplicate unit 29
    const int rowA = h * 30 + kk;                // h0: i-row, h1: f-row
    const int rowB = 60 + h * 30 + kk;           // h0: g-row, h1: o-row

    __shared__ __align__(16) float h1buf[2][32];   // h1(t) at parity t&1 (30 used)
    __shared__ __align__(16) float pbuf[2][128];   // partial pairs, parity t&1
    if (tid < 64) ((float*)h1buf)[tid] = 0.0f;
    for (int i = tid; i < 256; i += 192) ((float*)pbuf)[i] = 0.0f;
    __syncthreads();

    // ---- shared-name per-wave weights: union live set stays ~60 regs ----
    float wr0[30], wr1[30];   // wave0: whh1 rowA/rowB; wave1: wih2; wave2: whh2
    float bb0 = 0.0f, bb1 = 0.0f;   // wave0: b1 rows; wave1: b2 rows
    float wxa = 0.0f, wxb = 0.0f;   // wave0 only: w_ih1 rows
    float wfck = 0.0f;              // wave2 only
    if (wave == 0) {
#pragma unroll
        for (int j = 0; j < 30; ++j) {
            wr0[j] = w_hh1[rowA * HID + j];
            wr1[j] = w_hh1[rowB * HID + j];
        }
        bb0 = b_ih1[rowA] + b_hh1[rowA];
        bb1 = b_ih1[rowB] + b_hh1[rowB];
        wxa = w_ih1[rowA];
        wxb = w_ih1[rowB];
    } else if (wave == 1) {
#pragma unroll
        for (int j = 0; j < 30; ++j) {
            wr0[j] = w_ih2[rowA * HID + j];
            wr1[j] = w_ih2[rowB * HID + j];
        }
        bb0 = b_ih2[rowA] + b_hh2[rowA];
        bb1 = b_ih2[rowB] + b_hh2[rowB];
    } else {
#pragma unroll
        for (int j = 0; j < 30; ++j) {
            wr0[j] = w_hh2[rowA * HID + j];
            wr1[j] = w_hh2[rowB * HID + j];
        }
        wfck = (h && k < HID) ? w_fc[k] : 0.0f;
    }
#pragma unroll
    for (int j = 0; j < 30; ++j) { pinf(wr0[j]); pinf(wr1[j]); }
    pinf(bb0); pinf(bb1); pinf(wxa); pinf(wxb); pinf(wfck);
    const float bfc = __int_as_float(__builtin_amdgcn_readfirstlane(__float_as_int(b_fc[0])));

    // gate-y activation constants: h0 -> tanh (g), h1 -> sigmoid (o)
    const float cy = h ? (-L2E) : (-2.0f * L2E);
    const float my = h ? 1.0f : 2.0f;
    const float ay = h ? 0.0f : -1.0f;

    float hh  = 0.0f;   // wave0: h1[kk] (valid in h=1 half); wave2: h2[kk]
    float cst = 0.0f;   // wave0: c1;    wave2: c2
    const float* xp   = x   + (size_t)b * TSTEPS;
    float*       outp = out + (size_t)b * TSTEPS;

    // x double-buffer: xv_cur covers [tt & ~63, +64), xv_nxt the following chunk
    float xv_cur = 0.0f, xv_nxt = 0.0f;
    if (wave == 0) { xv_cur = xp[lane]; xv_nxt = xp[64 + lane]; }

    for (int tt = 0; tt <= TSTEPS + 1; ++tt) {
        lds_barrier();   // orders h1buf (w0->w1) and pbuf (w1->w2) handoffs + WAR

        if (wave == 0) {
            if (tt < TSTEPS) {
                // ---------- layer 1, step tt (register self-recurrence) ----------
                if ((tt & 63) == 0 && tt) {
                    xv_cur = xv_nxt;                         // loaded 64 iters ago
                    if (tt + 64 < TSTEPS) xv_nxt = xp[tt + 64 + lane];
                }
                const float xt = rl(xv_cur, tt & 63);
                float a0 = fmaf(xt, wxa, bb0), a1 = 0.0f;   // rowA: i/f
                float c0 = fmaf(xt, wxb, bb1), c1a = 0.0f;  // rowB: g/o
#pragma unroll
                for (int j = 0; j < 30; j += 2) {
                    const float hj0 = rl(hh, 32 + j);       // h1(tt-1)[j]
                    const float hj1 = rl(hh, 33 + j);
                    a0  = fmaf(wr0[j],     hj0, a0);
                    c0  = fmaf(wr1[j],     hj0, c0);
                    a1  = fmaf(wr0[j + 1], hj1, a1);
                    c1a = fmaf(wr1[j + 1], hj1, c1a);
                }
                const float preA = a0 + a1, preB = c0 + c1a;
                const float gx = frcp(1.0f + fexp2(preA * (-L2E)));           // i / f
                const float gy = fmaf(frcp(1.0f + fexp2(preB * cy)), my, ay); // g / o
                const float p  = gx * gy;                    // h0: i*g
                const float px = other_half(p, h);
                cst = fmaf(gx, cst, px);                     // h1: f*c1 + i*g
                const float tc = fmaf(2.0f, frcp(1.0f + fexp2(cst * (-2.0f * L2E))), -1.0f);
                hh = gy * tc;                                // h1: h1(tt)[kk]
                if (h) h1buf[tt & 1][kk] = hh;               // publish for wave1
            }
        } else if (wave == 1) {
            if (tt >= 1 && tt <= TSTEPS) {
                // ---------- partial: W_ih2 * h1(tt-1) + b2 ----------
                const v4f* rd = (const v4f*)h1buf[(tt - 1) & 1];
                float a0 = bb0, a1 = 0.0f;     // rowA partial
                float c0 = bb1, c1a = 0.0f;    // rowB partial
#pragma unroll
                for (int c = 0; c < 7; ++c) {
                    const v4f hc = rd[c];                    // broadcast read
                    a0  = fmaf(wr0[4 * c + 0], hc.x, a0);
                    c0  = fmaf(wr1[4 * c + 0], hc.x, c0);
                    a1  = fmaf(wr0[4 * c + 1], hc.y, a1);
                    c1a = fmaf(wr1[4 * c + 1], hc.y, c1a);
                    a0  = fmaf(wr0[4 * c + 2], hc.z, a0);
                    c0  = fmaf(wr1[4 * c + 2], hc.z, c0);
                    a1  = fmaf(wr0[4 * c + 3], hc.w, a1);
                    c1a = fmaf(wr1[4 * c + 3], hc.w, c1a);
                }
                const v2f tl = ((const v2f*)h1buf[(tt - 1) & 1])[14];  // j=28,29
                a0  = fmaf(wr0[28], tl.x, a0);
                c0  = fmaf(wr1[28], tl.x, c0);
                a1  = fmaf(wr0[29], tl.y, a1);
                c1a = fmaf(wr1[29], tl.y, c1a);
                v2f pr;
                pr.x = a0 + a1;
                pr.y = c0 + c1a;
                ((v2f*)pbuf[(tt - 1) & 1])[lane] = pr;       // handoff to wave2
            }
        } else {
            if (tt >= 2) {
                // ---------- layer 2, step tt-2 (register self-recurrence) ----------
                const v2f part = ((const v2f*)pbuf[tt & 1])[lane];  // (tt-2)&1 == tt&1
                float a0 = 0.0f, a1 = 0.0f, c0 = 0.0f, c1a = 0.0f;
#pragma unroll
                for (int j = 0; j < 30; j += 2) {
                    const float hj0 = rl(hh, 32 + j);        // h2(tt-3)[j]
                    const float hj1 = rl(hh, 33 + j);
                    a0  = fmaf(wr0[j],     hj0, a0);
                    c0  = fmaf(wr1[j],     hj0, c0);
                    a1  = fmaf(wr0[j + 1], hj1, a1);
                    c1a = fmaf(wr1[j + 1], hj1, c1a);
                }
                const float preA = (a0 + a1) + part.x;
                const float preB = (c0 + c1a) + part.y;
                const float gx = frcp(1.0f + fexp2(preA * (-L2E)));
                const float gy = fmaf(frcp(1.0f + fexp2(preB * cy)), my, ay);
                const float p  = gx * gy;
                const float px = other_half(p, h);
                cst = fmaf(gx, cst, px);                     // c2
                const float tc = fmaf(2.0f, frcp(1.0f + fexp2(cst * (-2.0f * L2E))), -1.0f);
                hh = gy * tc;                                // h2(tt-2)[kk] in h=1
                // fc head; the scalar store stays in flight (no vmcnt drain anywhere)
                const float s = dpp_reduce63(wfck * hh);
                if (lane == 63) outp[tt - 2] = s + bfc;
            }
        }
    }
}

extern "C" void kernel_launch(void* const* d_in, const int* in_sizes, int n_in,
                              void* d_out, int out_size, void* d_ws, size_t ws_size,
                              hipStream_t stream)
{
    const float* x     = (const float*)d_in[0];
    const float* w_ih1 = (const float*)d_in[1];
    const float* w_hh1 = (const float*)d_in[2];
    const float* b_ih1 = (const float*)d_in[3];
    const float* b_hh1 = (const float*)d_in[4];
    const float* w_ih2 = (const float*)d_in[5];
    const float* w_hh2 = (const float*)d_in[6];
    const float* b_ih2 = (const float*)d_in[7];
    const float* b_hh2 = (const float*)d_in[8];
    const float* w_fc  = (const float*)d_in[9];
    const float* b_fc  = (const float*)d_in[10];
    float* out = (float*)d_out;

    lstm2_kernel<<<BATCH, 192, 0, stream>>>(x, w_ih1, w_hh1, b_ih1, b_hh1,
                                            w_ih2, w_hh2, b_ih2, b_hh2,
                                            w_fc, b_fc, out);
}